// Round 1
// baseline (1768.996 us; speedup 1.0000x reference)
//
#include <hip/hip_runtime.h>
#include <hip/hip_bf16.h>

#define B 8
#define C 192
#define OC 576
#define H 128
#define W 128
#define N (H*W)          // 16384
#define HEADS 4
#define CH 48            // C / HEADS

#define BM 64
#define BN 128
#define BK 16

// ---------------------------------------------------------------------------
// K0: zero the atomically-accumulated scratch (normsq, Gram) every call
// (harness re-poisons ws to 0xAA before each timed launch)
// ---------------------------------------------------------------------------
__global__ void k_zero(float* __restrict__ normsq, float* __restrict__ G) {
    int i = blockIdx.x * 256 + threadIdx.x;
    if (i < B * 2 * C) normsq[i] = 0.0f;
    if (i < B * HEADS * CH * CH) G[i] = 0.0f;
}

// ---------------------------------------------------------------------------
// K1: mask_single[b][p] = sum_c cm_w[c] * ((Input-x) > thr)   (fp32 exact)
// ---------------------------------------------------------------------------
__global__ __launch_bounds__(256) void k_mask(
    const float* __restrict__ x, const float* __restrict__ inp,
    const float* __restrict__ cm_w, const float* __restrict__ thr,
    float* __restrict__ mask_single) {
    __shared__ float cw[C];
    int tid = threadIdx.x;
    if (tid < C) cw[tid] = cm_w[tid];
    __syncthreads();
    int idx = blockIdx.x * 256 + tid;           // b*N + p
    int b = idx >> 14;
    int p = idx & (N - 1);
    float th = thr[0];
    size_t base = (size_t)b * C * N + p;
    float s = 0.0f;
    #pragma unroll 8
    for (int c2 = 0; c2 < C; ++c2) {
        float d = inp[base + (size_t)c2 * N] - x[base + (size_t)c2 * N];
        s += (d > th) ? cw[c2] : 0.0f;
    }
    mask_single[idx] = s;
}

// ---------------------------------------------------------------------------
// K2: qkv 1x1 conv as per-batch GEMM: out[b][o][n] = sum_c w[o][c]*x[b][c][n]
// fp32 compute, bf16 store. BM=64 (o), BN=128 (n), BK=16, 4x8 thread tiles.
// ---------------------------------------------------------------------------
__global__ __launch_bounds__(256) void k_qkv_gemm(
    const float* __restrict__ x, const float* __restrict__ w,
    __hip_bfloat16* __restrict__ out) {
    __shared__ float As[BK][BM];       // As[k][m] = w[m0+m][k0+k]
    __shared__ float Bs[BK][BN + 4];   // Bs[k][n] = x[b][k0+k][n0+n]
    int b = blockIdx.z;
    int m0 = blockIdx.y * BM;
    int n0 = blockIdx.x * BN;
    int tid = threadIdx.x;
    int tm = (tid >> 4) * 4;   // 0..60
    int tn = (tid & 15) * 8;   // 0..120
    float acc[4][8] = {};
    const float* xb = x + (size_t)b * C * N;
    for (int k0 = 0; k0 < C; k0 += BK) {
        #pragma unroll
        for (int l = tid; l < BM * BK; l += 256) {
            int m = l >> 4, k = l & 15;
            As[k][m] = w[(size_t)(m0 + m) * C + k0 + k];
        }
        #pragma unroll
        for (int l = tid; l < BK * BN; l += 256) {
            int k = l >> 7, n = l & 127;
            Bs[k][n] = xb[(size_t)(k0 + k) * N + n0 + n];
        }
        __syncthreads();
        #pragma unroll
        for (int k = 0; k < BK; ++k) {
            float4 a = *(const float4*)&As[k][tm];
            float4 b0 = *(const float4*)&Bs[k][tn];
            float4 b1 = *(const float4*)&Bs[k][tn + 4];
            float av[4] = {a.x, a.y, a.z, a.w};
            float bv[8] = {b0.x, b0.y, b0.z, b0.w, b1.x, b1.y, b1.z, b1.w};
            #pragma unroll
            for (int i = 0; i < 4; ++i)
                #pragma unroll
                for (int j = 0; j < 8; ++j)
                    acc[i][j] += av[i] * bv[j];
        }
        __syncthreads();
    }
    __hip_bfloat16* ob = out + ((size_t)b * OC + m0) * N + n0;
    #pragma unroll
    for (int i = 0; i < 4; ++i) {
        union { __hip_bfloat16 h[8]; uint4 u; } pk;
        #pragma unroll
        for (int j = 0; j < 8; ++j) pk.h[j] = (__hip_bfloat16)acc[i][j];
        *(uint4*)&ob[(size_t)(tm + i) * N + tn] = pk.u;
    }
}

// ---------------------------------------------------------------------------
// K3: depthwise 3x3 (SAME, correlation) + mask multiply on q,k + sum-of-squares
// per (b, channel) for q,k (for the folded l2norm). bf16 in/out, fp32 math.
// ---------------------------------------------------------------------------
__global__ __launch_bounds__(256) void k_dwconv(
    const __hip_bfloat16* __restrict__ qkv_raw, const float* __restrict__ dw_w,
    const float* __restrict__ mask_single, __hip_bfloat16* __restrict__ qkv_dw,
    float* __restrict__ normsq) {
    int b = blockIdx.z, o = blockIdx.y;
    int p = blockIdx.x * 256 + threadIdx.x;   // 0..16383
    int y = p >> 7, xq = p & 127;
    const __hip_bfloat16* in = qkv_raw + ((size_t)b * OC + o) * N;
    const float* wp = dw_w + o * 9;
    float s = 0.0f;
    #pragma unroll
    for (int dy = -1; dy <= 1; ++dy) {
        int yy = y + dy;
        if (yy < 0 || yy >= H) continue;
        #pragma unroll
        for (int dx = -1; dx <= 1; ++dx) {
            int xx = xq + dx;
            if (xx < 0 || xx >= W) continue;
            s += wp[(dy + 1) * 3 + (dx + 1)] * (float)in[yy * W + xx];
        }
    }
    bool is_qk = (o < 2 * C);   // uniform per block
    if (is_qk) s *= mask_single[b * N + p];
    __hip_bfloat16 hv = (__hip_bfloat16)s;
    qkv_dw[((size_t)b * OC + o) * N + p] = hv;
    if (is_qk) {
        float v2 = (float)hv;          // consistent with what Gram will read
        float sq = v2 * v2;
        #pragma unroll
        for (int off = 32; off > 0; off >>= 1) sq += __shfl_down(sq, off);
        __shared__ float red[4];
        if ((threadIdx.x & 63) == 0) red[threadIdx.x >> 6] = sq;
        __syncthreads();
        if (threadIdx.x == 0)
            atomicAdd(&normsq[b * 2 * C + o], red[0] + red[1] + red[2] + red[3]);
    }
}

// ---------------------------------------------------------------------------
// K4: Gram matrices G[b][h][i][j] = sum_n q[b][h*48+i][n]*k[b][h*48+j][n]
// grid (32 n-chunks of 512, HEADS, B); 3x3 register tiles over 48x48.
// ---------------------------------------------------------------------------
__global__ __launch_bounds__(256) void k_gram(
    const __hip_bfloat16* __restrict__ qkv_dw, float* __restrict__ G) {
    int b = blockIdx.z, hh = blockIdx.y, chunk = blockIdx.x;
    int n_base = chunk * 512;
    __shared__ float qs[CH][68];
    __shared__ float ks[CH][68];
    int tid = threadIdx.x;
    int i0 = (tid >> 4) * 3;   // 0..45
    int j0 = (tid & 15) * 3;   // 0..45
    float acc[3][3] = {};
    const __hip_bfloat16* qb = qkv_dw + ((size_t)b * OC + hh * CH) * N;
    const __hip_bfloat16* kb = qkv_dw + ((size_t)b * OC + C + hh * CH) * N;
    for (int s = 0; s < 8; ++s) {
        int nb = n_base + s * 64;
        #pragma unroll
        for (int l = tid; l < CH * 64; l += 256) {
            int r = l >> 6, nn = l & 63;
            qs[r][nn] = (float)qb[(size_t)r * N + nb + nn];
            ks[r][nn] = (float)kb[(size_t)r * N + nb + nn];
        }
        __syncthreads();
        #pragma unroll
        for (int nn = 0; nn < 64; nn += 4) {
            float4 qv[3], kv[3];
            #pragma unroll
            for (int r = 0; r < 3; ++r) qv[r] = *(const float4*)&qs[i0 + r][nn];
            #pragma unroll
            for (int r = 0; r < 3; ++r) kv[r] = *(const float4*)&ks[j0 + r][nn];
            #pragma unroll
            for (int a = 0; a < 3; ++a)
                #pragma unroll
                for (int c2 = 0; c2 < 3; ++c2)
                    acc[a][c2] += qv[a].x * kv[c2].x + qv[a].y * kv[c2].y +
                                  qv[a].z * kv[c2].z + qv[a].w * kv[c2].w;
        }
        __syncthreads();
    }
    float* Gb = G + (size_t)(b * HEADS + hh) * CH * CH;
    #pragma unroll
    for (int a = 0; a < 3; ++a)
        #pragma unroll
        for (int c2 = 0; c2 < 3; ++c2)
            atomicAdd(&Gb[(i0 + a) * CH + (j0 + c2)], acc[a][c2]);
}

// ---------------------------------------------------------------------------
// K5: logits = G*temp/(|q_i||k_j|), softmax over j, then fold attn into proj:
// W_eff[b][o][h*48+j] = sum_i proj_w[o][h*48+i] * attn[h][i][j]
// grid (B, 6 o-chunks of 32)
// ---------------------------------------------------------------------------
__global__ __launch_bounds__(256) void k_attn_weff(
    const float* __restrict__ G, const float* __restrict__ normsq,
    const float* __restrict__ temperature, const float* __restrict__ proj_w,
    float* __restrict__ W_eff) {
    int b = blockIdx.x;
    int o_base = blockIdx.y * 32;
    __shared__ float attn[HEADS][CH][CH];
    __shared__ float inv_n[2 * C];
    int tid = threadIdx.x;
    for (int l = tid; l < 2 * C; l += 256)
        inv_n[l] = 1.0f / fmaxf(sqrtf(normsq[b * 2 * C + l]), 1e-12f);
    __syncthreads();
    if (tid < HEADS * CH) {
        int hh = tid / CH, i = tid % CH;
        float iq = inv_n[hh * CH + i] * temperature[hh];
        const float* Gr = G + ((size_t)(b * HEADS + hh) * CH + i) * CH;
        float mx = -1e30f;
        for (int j = 0; j < CH; ++j) {
            float l2 = Gr[j] * iq * inv_n[C + hh * CH + j];
            attn[hh][i][j] = l2;
            mx = fmaxf(mx, l2);
        }
        float sm = 0.0f;
        for (int j = 0; j < CH; ++j) {
            float e = expf(attn[hh][i][j] - mx);
            attn[hh][i][j] = e;
            sm += e;
        }
        float is = 1.0f / sm;
        for (int j = 0; j < CH; ++j) attn[hh][i][j] *= is;
    }
    __syncthreads();
    for (int idx = tid; idx < 32 * C; idx += 256) {
        int o = o_base + idx / C, cp = idx % C;
        int hh = cp / CH, j = cp % CH;
        const float* pw = proj_w + (size_t)o * C + hh * CH;
        float s = 0.0f;
        #pragma unroll 8
        for (int i = 0; i < CH; ++i) s += pw[i] * attn[hh][i][j];
        W_eff[((size_t)b * C + o) * C + cp] = s;
    }
}

// ---------------------------------------------------------------------------
// K6: final GEMM: out[b][o][n] = sum_c W_eff[b][o][c] * v[b][c][n]  (fp32 out)
// ---------------------------------------------------------------------------
__global__ __launch_bounds__(256) void k_out_gemm(
    const __hip_bfloat16* __restrict__ qkv_dw, const float* __restrict__ W_eff,
    float* __restrict__ out) {
    __shared__ float As[BK][BM];
    __shared__ float Bs[BK][BN + 4];
    int b = blockIdx.z;
    int m0 = blockIdx.y * BM;
    int n0 = blockIdx.x * BN;
    int tid = threadIdx.x;
    int tm = (tid >> 4) * 4;
    int tn = (tid & 15) * 8;
    float acc[4][8] = {};
    const float* wb = W_eff + (size_t)b * C * C;
    const __hip_bfloat16* vb = qkv_dw + ((size_t)b * OC + 2 * C) * N;
    for (int k0 = 0; k0 < C; k0 += BK) {
        #pragma unroll
        for (int l = tid; l < BM * BK; l += 256) {
            int m = l >> 4, k = l & 15;
            As[k][m] = wb[(size_t)(m0 + m) * C + k0 + k];
        }
        #pragma unroll
        for (int l = tid; l < BK * BN; l += 256) {
            int k = l >> 7, n = l & 127;
            Bs[k][n] = (float)vb[(size_t)(k0 + k) * N + n0 + n];
        }
        __syncthreads();
        #pragma unroll
        for (int k = 0; k < BK; ++k) {
            float4 a = *(const float4*)&As[k][tm];
            float4 b0 = *(const float4*)&Bs[k][tn];
            float4 b1 = *(const float4*)&Bs[k][tn + 4];
            float av[4] = {a.x, a.y, a.z, a.w};
            float bv[8] = {b0.x, b0.y, b0.z, b0.w, b1.x, b1.y, b1.z, b1.w};
            #pragma unroll
            for (int i = 0; i < 4; ++i)
                #pragma unroll
                for (int j = 0; j < 8; ++j)
                    acc[i][j] += av[i] * bv[j];
        }
        __syncthreads();
    }
    float* ob = out + ((size_t)b * C + m0) * N + n0;
    #pragma unroll
    for (int i = 0; i < 4; ++i) {
        *(float4*)&ob[(size_t)(tm + i) * N + tn] =
            make_float4(acc[i][0], acc[i][1], acc[i][2], acc[i][3]);
        *(float4*)&ob[(size_t)(tm + i) * N + tn + 4] =
            make_float4(acc[i][4], acc[i][5], acc[i][6], acc[i][7]);
    }
}

// ---------------------------------------------------------------------------
extern "C" void kernel_launch(void* const* d_in, const int* in_sizes, int n_in,
                              void* d_out, int out_size, void* d_ws, size_t ws_size,
                              hipStream_t stream) {
    const float* x           = (const float*)d_in[0];
    const float* inp         = (const float*)d_in[1];
    const float* qkv_w       = (const float*)d_in[2];
    const float* dw_w        = (const float*)d_in[3];
    const float* proj_w      = (const float*)d_in[4];
    const float* cm_w        = (const float*)d_in[5];
    const float* temperature = (const float*)d_in[6];
    const float* threshold   = (const float*)d_in[7];
    float* out = (float*)d_out;

    // workspace layout (bytes): total ~304 MB
    char* ws = (char*)d_ws;
    const size_t S1 = (size_t)B * OC * N * sizeof(__hip_bfloat16);  // 151 MB
    __hip_bfloat16* qkv_raw = (__hip_bfloat16*)ws;
    __hip_bfloat16* qkv_dw  = (__hip_bfloat16*)(ws + S1);
    float* mask_single = (float*)(ws + 2 * S1);
    float* normsq = (float*)(ws + 2 * S1 + (size_t)B * N * sizeof(float));
    float* G      = normsq + B * 2 * C;
    float* W_eff  = G + B * HEADS * CH * CH;

    k_zero<<<dim3((B * HEADS * CH * CH + 255) / 256), 256, 0, stream>>>(normsq, G);
    k_mask<<<dim3(B * N / 256), 256, 0, stream>>>(x, inp, cm_w, threshold, mask_single);
    k_qkv_gemm<<<dim3(N / BN, OC / BM, B), 256, 0, stream>>>(x, qkv_w, qkv_raw);
    k_dwconv<<<dim3(N / 256, OC, B), 256, 0, stream>>>(qkv_raw, dw_w, mask_single, qkv_dw, normsq);
    k_gram<<<dim3(32, HEADS, B), 256, 0, stream>>>(qkv_dw, G);
    k_attn_weff<<<dim3(B, 6), 256, 0, stream>>>(G, normsq, temperature, proj_w, W_eff);
    k_out_gemm<<<dim3(N / BN, C / BM, B), 256, 0, stream>>>(qkv_dw, W_eff, out);
}

// Round 2
// 856.290 us; speedup vs baseline: 2.0659x; 2.0659x over previous
//
#include <hip/hip_runtime.h>
#include <hip/hip_bf16.h>

#define B 8
#define C 192
#define OC 576
#define H 128
#define W 128
#define N (H*W)          // 16384
#define HEADS 4
#define CH 48            // C / HEADS

typedef __attribute__((ext_vector_type(8))) short short8;
typedef __attribute__((ext_vector_type(4))) float floatx4;

__device__ __forceinline__ float bf2f(unsigned short u) {
    union { unsigned int i; float f; } v; v.i = ((unsigned int)u) << 16; return v.f;
}
__device__ __forceinline__ unsigned short f2bf(float f) {
    __hip_bfloat16 h = (__hip_bfloat16)f;
    unsigned short u; __builtin_memcpy(&u, &h, 2); return u;
}

// ---------------------------------------------------------------------------
// K0: zero atomically-accumulated scratch
// ---------------------------------------------------------------------------
__global__ void k_zero(float* __restrict__ normsq, float* __restrict__ G) {
    int i = blockIdx.x * 256 + threadIdx.x;
    if (i < B * 2 * C) normsq[i] = 0.0f;
    if (i < B * HEADS * CH * CH) G[i] = 0.0f;
}

// ---------------------------------------------------------------------------
// K1: mask_single[b][p] = sum_c cm_w[c] * ((Input-x) > thr)
// ---------------------------------------------------------------------------
__global__ __launch_bounds__(256) void k_mask(
    const float* __restrict__ x, const float* __restrict__ inp,
    const float* __restrict__ cm_w, const float* __restrict__ thr,
    float* __restrict__ mask_single) {
    __shared__ float cw[C];
    int tid = threadIdx.x;
    if (tid < C) cw[tid] = cm_w[tid];
    __syncthreads();
    int idx = blockIdx.x * 256 + tid;
    int b = idx >> 14;
    int p = idx & (N - 1);
    float th = thr[0];
    size_t base = (size_t)b * C * N + p;
    float s = 0.0f;
    #pragma unroll 8
    for (int c2 = 0; c2 < C; ++c2) {
        float d = inp[base + (size_t)c2 * N] - x[base + (size_t)c2 * N];
        s += (d > th) ? cw[c2] : 0.0f;
    }
    mask_single[idx] = s;
}

// ---------------------------------------------------------------------------
// K2: transpose-convert x fp32 [b][c][n] -> xt bf16-bits [b][n][c]
// ---------------------------------------------------------------------------
__global__ __launch_bounds__(256) void k_xpose_x(
    const float* __restrict__ src, unsigned short* __restrict__ dst) {
    __shared__ unsigned short t[64][C + 2];
    int tid = threadIdx.x;
    int b = blockIdx.y, n0 = blockIdx.x * 64;
    const float* sb = src + (size_t)b * C * N;
    for (int i = tid; i < C * 64; i += 256) {
        int c = i >> 6, nn = i & 63;
        t[nn][c] = f2bf(sb[(size_t)c * N + n0 + nn]);
    }
    __syncthreads();
    unsigned short* db = dst + ((size_t)b * N + n0) * C;
    for (int i = tid; i < 64 * (C / 8); i += 256) {
        int nn = i / (C / 8), ch = i % (C / 8);
        union { unsigned short h[8]; uint4 u; } pk;
        #pragma unroll
        for (int j = 0; j < 8; ++j) pk.h[j] = t[nn][ch * 8 + j];
        *(uint4*)&db[(size_t)nn * C + ch * 8] = pk.u;
    }
}

// ---------------------------------------------------------------------------
// K3: qkv 1x1 conv via MFMA bf16: qkv_raw[b][o][n] = sum_c w[o][c]*x[b][c][n]
// A = qkv_w (fp32, converted in staging), B = xt bf16 [n][c]. Tile 64m x 256n.
// ---------------------------------------------------------------------------
#define PAD 40
__global__ __launch_bounds__(256) void k_qkv_mfma(
    const unsigned short* __restrict__ xt, const float* __restrict__ w,
    unsigned short* __restrict__ out) {
    __shared__ __align__(16) unsigned short As[64][PAD];
    __shared__ __align__(16) unsigned short Bs[256][PAD];
    int b = blockIdx.z, m0 = blockIdx.y * 64, n0 = blockIdx.x * 256;
    int tid = threadIdx.x, wave = tid >> 6, lane = tid & 63;
    int l15 = lane & 15, quad = lane >> 4;
    floatx4 acc[4][4];
    #pragma unroll
    for (int i = 0; i < 4; ++i)
        #pragma unroll
        for (int j = 0; j < 4; ++j) acc[i][j] = (floatx4){0.f, 0.f, 0.f, 0.f};
    const unsigned short* xb = xt + (size_t)b * N * C;
    for (int k0 = 0; k0 < C; k0 += 32) {
        {   // stage A: 64 rows x 32 k from fp32 weights
            int m = tid >> 2, ko = tid & 3;
            const float* wr = w + (size_t)(m0 + m) * C + k0 + ko * 8;
            float4 f0 = *(const float4*)&wr[0];
            float4 f1 = *(const float4*)&wr[4];
            unsigned int* dp = (unsigned int*)&As[m][ko * 8];
            dp[0] = (unsigned int)f2bf(f0.x) | ((unsigned int)f2bf(f0.y) << 16);
            dp[1] = (unsigned int)f2bf(f0.z) | ((unsigned int)f2bf(f0.w) << 16);
            dp[2] = (unsigned int)f2bf(f1.x) | ((unsigned int)f2bf(f1.y) << 16);
            dp[3] = (unsigned int)f2bf(f1.z) | ((unsigned int)f2bf(f1.w) << 16);
        }
        #pragma unroll
        for (int t = 0; t < 4; ++t) {   // stage B: 256 rows x 32 k
            int i = tid + t * 256;
            int n = i >> 2, ko = i & 3;
            *(uint4*)&Bs[n][ko * 8] = *(const uint4*)&xb[(size_t)(n0 + n) * C + k0 + ko * 8];
        }
        __syncthreads();
        short8 af[4], bf[4];
        #pragma unroll
        for (int mt = 0; mt < 4; ++mt)
            af[mt] = *(const short8*)&As[mt * 16 + l15][quad * 8];
        #pragma unroll
        for (int nt = 0; nt < 4; ++nt)
            bf[nt] = *(const short8*)&Bs[wave * 64 + nt * 16 + l15][quad * 8];
        #pragma unroll
        for (int mt = 0; mt < 4; ++mt)
            #pragma unroll
            for (int nt = 0; nt < 4; ++nt)
                acc[mt][nt] = __builtin_amdgcn_mfma_f32_16x16x32_bf16(
                    af[mt], bf[nt], acc[mt][nt], 0, 0, 0);
        __syncthreads();
    }
    unsigned short* ob = out + (size_t)b * OC * N;
    #pragma unroll
    for (int mt = 0; mt < 4; ++mt)
        #pragma unroll
        for (int r = 0; r < 4; ++r) {
            int o = m0 + mt * 16 + quad * 4 + r;
            #pragma unroll
            for (int nt = 0; nt < 4; ++nt)
                ob[(size_t)o * N + n0 + wave * 64 + nt * 16 + l15] =
                    f2bf(acc[mt][nt][r]);
        }
}

// ---------------------------------------------------------------------------
// K4: depthwise 3x3 (LDS-tiled) + mask + normsq. q,k -> qk[b][2C][n];
// v -> vbuf[b][C][n]. Block: one (b, channel, 32-row strip).
// ---------------------------------------------------------------------------
__global__ __launch_bounds__(256) void k_dwconv(
    const unsigned short* __restrict__ qkv_raw, const float* __restrict__ dw_w,
    const float* __restrict__ mask_single, unsigned short* __restrict__ qk_out,
    unsigned short* __restrict__ v_out, float* __restrict__ normsq) {
    __shared__ float tile[34][130];
    __shared__ float red[4];
    int tid = threadIdx.x;
    int b = blockIdx.z, o = blockIdx.y;
    int y0 = blockIdx.x * 32;
    const unsigned short* in = qkv_raw + ((size_t)b * OC + o) * N;
    for (int i = tid; i < 34 * 64; i += 256) {
        int r = i >> 6, dw = i & 63;
        int yy = y0 + r - 1;
        float fx = 0.f, fy = 0.f;
        if (yy >= 0 && yy < H) {
            unsigned int u = *(const unsigned int*)&in[yy * W + dw * 2];
            union { unsigned int i; float f; } lo, hi;
            lo.i = u << 16; hi.i = u & 0xffff0000u;
            fx = lo.f; fy = hi.f;
        }
        tile[r][1 + dw * 2] = fx;
        tile[r][2 + dw * 2] = fy;
        if (dw == 0) tile[r][0] = 0.f;
        if (dw == 63) tile[r][129] = 0.f;
    }
    __syncthreads();
    const float* wp = dw_w + o * 9;
    float w00 = wp[0], w01 = wp[1], w02 = wp[2];
    float w10 = wp[3], w11 = wp[4], w12 = wp[5];
    float w20 = wp[6], w21 = wp[7], w22 = wp[8];
    int c = tid & 127, g = tid >> 7;
    bool is_qk = (o < 2 * C);
    float m_acc = 0.f;
    int rbase = g * 16;
    float r0c0 = tile[rbase][c],     r0c1 = tile[rbase][c + 1],     r0c2 = tile[rbase][c + 2];
    float r1c0 = tile[rbase + 1][c], r1c1 = tile[rbase + 1][c + 1], r1c2 = tile[rbase + 1][c + 2];
    unsigned short* qkb = qk_out + ((size_t)b * 2 * C + o) * N;
    unsigned short* vb  = v_out + ((size_t)b * C + (o - 2 * C)) * N;
    const float* mb = mask_single + (size_t)b * N;
    #pragma unroll
    for (int rl = 0; rl < 16; ++rl) {
        int tr = rbase + rl + 2;
        float r2c0 = tile[tr][c], r2c1 = tile[tr][c + 1], r2c2 = tile[tr][c + 2];
        float s = w00 * r0c0 + w01 * r0c1 + w02 * r0c2
                + w10 * r1c0 + w11 * r1c1 + w12 * r1c2
                + w20 * r2c0 + w21 * r2c1 + w22 * r2c2;
        int p = (y0 + rbase + rl) * W + c;
        if (is_qk) s *= mb[p];
        unsigned short hv = f2bf(s);
        if (is_qk) {
            qkb[p] = hv;
            float fv = bf2f(hv);
            m_acc += fv * fv;
        } else {
            vb[p] = hv;
        }
        r0c0 = r1c0; r0c1 = r1c1; r0c2 = r1c2;
        r1c0 = r2c0; r1c1 = r2c1; r1c2 = r2c2;
    }
    if (is_qk) {
        #pragma unroll
        for (int off = 32; off > 0; off >>= 1) m_acc += __shfl_down(m_acc, off);
        if ((tid & 63) == 0) red[tid >> 6] = m_acc;
        __syncthreads();
        if (tid == 0)
            atomicAdd(&normsq[b * 2 * C + o], red[0] + red[1] + red[2] + red[3]);
    }
}

// ---------------------------------------------------------------------------
// K5: transpose v bf16 [b][c][n] -> v_t [b][n][c]
// ---------------------------------------------------------------------------
__global__ __launch_bounds__(256) void k_xpose_v(
    const unsigned short* __restrict__ src, unsigned short* __restrict__ dst) {
    __shared__ unsigned short t[64][C + 2];
    int tid = threadIdx.x;
    int b = blockIdx.y, n0 = blockIdx.x * 64;
    const unsigned short* sb = src + (size_t)b * C * N;
    for (int i = tid; i < C * 32; i += 256) {
        int c = i >> 5, np = i & 31;
        unsigned int u = *(const unsigned int*)&sb[(size_t)c * N + n0 + np * 2];
        t[np * 2][c] = (unsigned short)(u & 0xffffu);
        t[np * 2 + 1][c] = (unsigned short)(u >> 16);
    }
    __syncthreads();
    unsigned short* db = dst + ((size_t)b * N + n0) * C;
    for (int i = tid; i < 64 * (C / 8); i += 256) {
        int nn = i / (C / 8), ch = i % (C / 8);
        union { unsigned short h[8]; uint4 u; } pk;
        #pragma unroll
        for (int j = 0; j < 8; ++j) pk.h[j] = t[nn][ch * 8 + j];
        *(uint4*)&db[(size_t)nn * C + ch * 8] = pk.u;
    }
}

// ---------------------------------------------------------------------------
// K6: Gram G[b][h][i][j] = sum_n q[i][n]*k[j][n]  (fp32, atomic partials)
// ---------------------------------------------------------------------------
__global__ __launch_bounds__(256) void k_gram(
    const unsigned short* __restrict__ qk, float* __restrict__ G) {
    int b = blockIdx.z, hh = blockIdx.y, chunk = blockIdx.x;
    int n_base = chunk * 512;
    __shared__ float qs[CH][68];
    __shared__ float ks[CH][68];
    int tid = threadIdx.x;
    int i0 = (tid >> 4) * 3;
    int j0 = (tid & 15) * 3;
    float acc[3][3] = {};
    const unsigned short* qb = qk + ((size_t)b * 2 * C + hh * CH) * N;
    const unsigned short* kb = qb + (size_t)C * N;
    for (int s = 0; s < 8; ++s) {
        int nb = n_base + s * 64;
        for (int l = tid; l < CH * 64; l += 256) {
            int r = l >> 6, nn = l & 63;
            qs[r][nn] = bf2f(qb[(size_t)r * N + nb + nn]);
            ks[r][nn] = bf2f(kb[(size_t)r * N + nb + nn]);
        }
        __syncthreads();
        #pragma unroll
        for (int nn = 0; nn < 64; nn += 4) {
            float4 qv[3], kv[3];
            #pragma unroll
            for (int r = 0; r < 3; ++r) qv[r] = *(const float4*)&qs[i0 + r][nn];
            #pragma unroll
            for (int r = 0; r < 3; ++r) kv[r] = *(const float4*)&ks[j0 + r][nn];
            #pragma unroll
            for (int a = 0; a < 3; ++a)
                #pragma unroll
                for (int c2 = 0; c2 < 3; ++c2)
                    acc[a][c2] += qv[a].x * kv[c2].x + qv[a].y * kv[c2].y +
                                  qv[a].z * kv[c2].z + qv[a].w * kv[c2].w;
        }
        __syncthreads();
    }
    float* Gb = G + (size_t)(b * HEADS + hh) * CH * CH;
    #pragma unroll
    for (int a = 0; a < 3; ++a)
        #pragma unroll
        for (int c2 = 0; c2 < 3; ++c2)
            atomicAdd(&Gb[(i0 + a) * CH + (j0 + c2)], acc[a][c2]);
}

// ---------------------------------------------------------------------------
// K7: softmax(G*temp/(|q||k|)) folded into proj -> W_eff bf16 [b][o][c]
// ---------------------------------------------------------------------------
__global__ __launch_bounds__(256) void k_attn_weff(
    const float* __restrict__ G, const float* __restrict__ normsq,
    const float* __restrict__ temperature, const float* __restrict__ proj_w,
    unsigned short* __restrict__ W_eff) {
    int b = blockIdx.x;
    int o_base = blockIdx.y * 32;
    __shared__ float attn[HEADS][CH][CH];
    __shared__ float inv_n[2 * C];
    int tid = threadIdx.x;
    for (int l = tid; l < 2 * C; l += 256)
        inv_n[l] = 1.0f / fmaxf(sqrtf(normsq[b * 2 * C + l]), 1e-12f);
    __syncthreads();
    if (tid < HEADS * CH) {
        int hh = tid / CH, i = tid % CH;
        float iq = inv_n[hh * CH + i] * temperature[hh];
        const float* Gr = G + ((size_t)(b * HEADS + hh) * CH + i) * CH;
        float mx = -1e30f;
        for (int j = 0; j < CH; ++j) {
            float l2 = Gr[j] * iq * inv_n[C + hh * CH + j];
            attn[hh][i][j] = l2;
            mx = fmaxf(mx, l2);
        }
        float sm = 0.0f;
        for (int j = 0; j < CH; ++j) {
            float e = expf(attn[hh][i][j] - mx);
            attn[hh][i][j] = e;
            sm += e;
        }
        float is = 1.0f / sm;
        for (int j = 0; j < CH; ++j) attn[hh][i][j] *= is;
    }
    __syncthreads();
    for (int idx = tid; idx < 32 * C; idx += 256) {
        int o = o_base + idx / C, cp = idx % C;
        int hh = cp / CH, j = cp % CH;
        const float* pw = proj_w + (size_t)o * C + hh * CH;
        float s = 0.0f;
        #pragma unroll 8
        for (int i = 0; i < CH; ++i) s += pw[i] * attn[hh][i][j];
        W_eff[((size_t)b * C + o) * C + cp] = f2bf(s);
    }
}

// ---------------------------------------------------------------------------
// K8: out = W_eff[b] (192x192) @ v_t^T -> fp32, MFMA. Tile 64m x 256n.
// ---------------------------------------------------------------------------
__global__ __launch_bounds__(256) void k_out_mfma(
    const unsigned short* __restrict__ vt, const unsigned short* __restrict__ W_eff,
    float* __restrict__ out) {
    __shared__ __align__(16) unsigned short As[64][PAD];
    __shared__ __align__(16) unsigned short Bs[256][PAD];
    int b = blockIdx.z, m0 = blockIdx.y * 64, n0 = blockIdx.x * 256;
    int tid = threadIdx.x, wave = tid >> 6, lane = tid & 63;
    int l15 = lane & 15, quad = lane >> 4;
    floatx4 acc[4][4];
    #pragma unroll
    for (int i = 0; i < 4; ++i)
        #pragma unroll
        for (int j = 0; j < 4; ++j) acc[i][j] = (floatx4){0.f, 0.f, 0.f, 0.f};
    const unsigned short* vb = vt + (size_t)b * N * C;
    const unsigned short* wb = W_eff + (size_t)b * C * C;
    for (int k0 = 0; k0 < C; k0 += 32) {
        {
            int m = tid >> 2, ko = tid & 3;
            *(uint4*)&As[m][ko * 8] = *(const uint4*)&wb[(size_t)(m0 + m) * C + k0 + ko * 8];
        }
        #pragma unroll
        for (int t = 0; t < 4; ++t) {
            int i = tid + t * 256;
            int n = i >> 2, ko = i & 3;
            *(uint4*)&Bs[n][ko * 8] = *(const uint4*)&vb[(size_t)(n0 + n) * C + k0 + ko * 8];
        }
        __syncthreads();
        short8 af[4], bf[4];
        #pragma unroll
        for (int mt = 0; mt < 4; ++mt)
            af[mt] = *(const short8*)&As[mt * 16 + l15][quad * 8];
        #pragma unroll
        for (int nt = 0; nt < 4; ++nt)
            bf[nt] = *(const short8*)&Bs[wave * 64 + nt * 16 + l15][quad * 8];
        #pragma unroll
        for (int mt = 0; mt < 4; ++mt)
            #pragma unroll
            for (int nt = 0; nt < 4; ++nt)
                acc[mt][nt] = __builtin_amdgcn_mfma_f32_16x16x32_bf16(
                    af[mt], bf[nt], acc[mt][nt], 0, 0, 0);
        __syncthreads();
    }
    float* ob = out + (size_t)b * C * N;
    #pragma unroll
    for (int mt = 0; mt < 4; ++mt)
        #pragma unroll
        for (int r = 0; r < 4; ++r) {
            int o = m0 + mt * 16 + quad * 4 + r;
            #pragma unroll
            for (int nt = 0; nt < 4; ++nt)
                ob[(size_t)o * N + n0 + wave * 64 + nt * 16 + l15] = acc[mt][nt][r];
        }
}

// ---------------------------------------------------------------------------
extern "C" void kernel_launch(void* const* d_in, const int* in_sizes, int n_in,
                              void* d_out, int out_size, void* d_ws, size_t ws_size,
                              hipStream_t stream) {
    const float* x           = (const float*)d_in[0];
    const float* inp         = (const float*)d_in[1];
    const float* qkv_w       = (const float*)d_in[2];
    const float* dw_w        = (const float*)d_in[3];
    const float* proj_w      = (const float*)d_in[4];
    const float* cm_w        = (const float*)d_in[5];
    const float* temperature = (const float*)d_in[6];
    const float* threshold   = (const float*)d_in[7];
    float* out = (float*)d_out;

    // workspace layout (~303.4 MB, with buffer reuse):
    //  [0, 151.0 MB)   qkv_raw  (bf16 B*OC*N)   -- reused as v_t after dwconv
    //  [151.0, 251.7)  qk       (bf16 B*2C*N)
    //  [251.7, 302.0)  xt       (bf16 B*N*C)    -- reused as vbuf by dwconv
    //  [302.0, ...)    mask, normsq, G, W_eff
    char* ws = (char*)d_ws;
    const size_t SZ_RAW = (size_t)B * OC * N * 2;      // 150,994,944
    const size_t SZ_QK  = (size_t)B * 2 * C * N * 2;   // 100,663,296
    const size_t SZ_XT  = (size_t)B * N * C * 2;       //  50,331,648
    unsigned short* qkv_raw = (unsigned short*)ws;
    unsigned short* v_t     = (unsigned short*)ws;                       // reuse
    unsigned short* qk      = (unsigned short*)(ws + SZ_RAW);
    unsigned short* xt      = (unsigned short*)(ws + SZ_RAW + SZ_QK);
    unsigned short* vbuf    = xt;                                        // reuse
    char* tail = ws + SZ_RAW + SZ_QK + SZ_XT;
    float* mask_single = (float*)tail;                       // B*N*4 = 524,288
    float* normsq = (float*)(tail + (size_t)B * N * 4);      // 12,288
    float* G = normsq + B * 2 * C;                           // 294,912
    unsigned short* W_eff = (unsigned short*)(G + B * HEADS * CH * CH);  // 589,824

    k_zero<<<dim3((B * HEADS * CH * CH + 255) / 256), 256, 0, stream>>>(normsq, G);
    k_mask<<<dim3(B * N / 256), 256, 0, stream>>>(x, inp, cm_w, threshold, mask_single);
    k_xpose_x<<<dim3(N / 64, B), 256, 0, stream>>>(x, xt);
    k_qkv_mfma<<<dim3(N / 256, OC / 64, B), 256, 0, stream>>>(xt, qkv_w, qkv_raw);
    k_dwconv<<<dim3(H / 32, OC, B), 256, 0, stream>>>(qkv_raw, dw_w, mask_single, qk, vbuf, normsq);
    k_xpose_v<<<dim3(N / 64, B), 256, 0, stream>>>(vbuf, v_t);
    k_gram<<<dim3(32, HEADS, B), 256, 0, stream>>>(qk, G);
    k_attn_weff<<<dim3(B, 6), 256, 0, stream>>>(G, normsq, temperature, proj_w, W_eff);
    k_out_mfma<<<dim3(N / 256, C / 64, B), 256, 0, stream>>>(v_t, W_eff, out);
}

// Round 3
// 554.206 us; speedup vs baseline: 3.1919x; 1.5451x over previous
//
#include <hip/hip_runtime.h>
#include <hip/hip_bf16.h>

#define B 8
#define C 192
#define OC 576
#define H 128
#define W 128
#define N (H*W)          // 16384
#define HEADS 4
#define CH 48            // C / HEADS

typedef __attribute__((ext_vector_type(8))) short short8;
typedef __attribute__((ext_vector_type(4))) float floatx4;

__device__ __forceinline__ float bf2f(unsigned short u) {
    union { unsigned int i; float f; } v; v.i = ((unsigned int)u) << 16; return v.f;
}
__device__ __forceinline__ unsigned short f2bf(float f) {
    __hip_bfloat16 h = (__hip_bfloat16)f;
    unsigned short u; __builtin_memcpy(&u, &h, 2); return u;
}

// ---------------------------------------------------------------------------
// K0: zero atomically-accumulated scratch
// ---------------------------------------------------------------------------
__global__ void k_zero(float* __restrict__ normsq, float* __restrict__ G) {
    int i = blockIdx.x * 256 + threadIdx.x;
    if (i < B * 2 * C) normsq[i] = 0.0f;
    if (i < B * HEADS * CH * CH) G[i] = 0.0f;
}

// ---------------------------------------------------------------------------
// K1 (fused): one pass over x+Input ->
//   mask_single[b][p] = sum_c cm_w[c]*((Input-x)>thr)
//   xt bf16 [b][n][c]  (transpose-convert of x)
// Block: 64 pixels. Thread (g=tid>>6, nn=tid&63) covers c in {g, g+4, ...}.
// ---------------------------------------------------------------------------
__global__ __launch_bounds__(256) void k_mask_xt(
    const float* __restrict__ x, const float* __restrict__ inp,
    const float* __restrict__ cm_w, const float* __restrict__ thr,
    float* __restrict__ mask_single, unsigned short* __restrict__ xt) {
    __shared__ unsigned short t[64][C + 2];
    __shared__ float partials[4][64];
    __shared__ float cw[C];
    int tid = threadIdx.x;
    if (tid < C) cw[tid] = cm_w[tid];
    __syncthreads();
    int b = blockIdx.y, n0 = blockIdx.x * 64;
    float th = thr[0];
    const float* xb = x + (size_t)b * C * N + n0;
    const float* ib = inp + (size_t)b * C * N + n0;
    int nn = tid & 63;
    float s = 0.0f;
    for (int i = tid; i < C * 64; i += 256) {
        int c = i >> 6;
        float xv = xb[(size_t)c * N + nn];
        float iv = ib[(size_t)c * N + nn];
        s += ((iv - xv) > th) ? cw[c] : 0.0f;
        t[nn][c] = f2bf(xv);
    }
    partials[tid >> 6][nn] = s;
    __syncthreads();
    if (tid < 64) {
        mask_single[(size_t)b * N + n0 + tid] =
            partials[0][tid] + partials[1][tid] + partials[2][tid] + partials[3][tid];
    }
    unsigned short* db = xt + ((size_t)b * N + n0) * C;
    for (int i = tid; i < 64 * (C / 8); i += 256) {
        int r = i / (C / 8), ch = i % (C / 8);
        union { unsigned short h[8]; uint4 u; } pk;
        #pragma unroll
        for (int j = 0; j < 8; ++j) pk.h[j] = t[r][ch * 8 + j];
        *(uint4*)&db[(size_t)r * C + ch * 8] = pk.u;
    }
}

// ---------------------------------------------------------------------------
// K3: qkv 1x1 conv via MFMA bf16: qkv_raw[b][o][n] = sum_c w[o][c]*x[b][c][n]
// ---------------------------------------------------------------------------
#define PAD 40
__global__ __launch_bounds__(256) void k_qkv_mfma(
    const unsigned short* __restrict__ xt, const float* __restrict__ w,
    unsigned short* __restrict__ out) {
    __shared__ __align__(16) unsigned short As[64][PAD];
    __shared__ __align__(16) unsigned short Bs[256][PAD];
    int b = blockIdx.z, m0 = blockIdx.y * 64, n0 = blockIdx.x * 256;
    int tid = threadIdx.x, wave = tid >> 6, lane = tid & 63;
    int l15 = lane & 15, quad = lane >> 4;
    floatx4 acc[4][4];
    #pragma unroll
    for (int i = 0; i < 4; ++i)
        #pragma unroll
        for (int j = 0; j < 4; ++j) acc[i][j] = (floatx4){0.f, 0.f, 0.f, 0.f};
    const unsigned short* xb = xt + (size_t)b * N * C;
    for (int k0 = 0; k0 < C; k0 += 32) {
        {
            int m = tid >> 2, ko = tid & 3;
            const float* wr = w + (size_t)(m0 + m) * C + k0 + ko * 8;
            float4 f0 = *(const float4*)&wr[0];
            float4 f1 = *(const float4*)&wr[4];
            unsigned int* dp = (unsigned int*)&As[m][ko * 8];
            dp[0] = (unsigned int)f2bf(f0.x) | ((unsigned int)f2bf(f0.y) << 16);
            dp[1] = (unsigned int)f2bf(f0.z) | ((unsigned int)f2bf(f0.w) << 16);
            dp[2] = (unsigned int)f2bf(f1.x) | ((unsigned int)f2bf(f1.y) << 16);
            dp[3] = (unsigned int)f2bf(f1.z) | ((unsigned int)f2bf(f1.w) << 16);
        }
        #pragma unroll
        for (int t = 0; t < 4; ++t) {
            int i = tid + t * 256;
            int n = i >> 2, ko = i & 3;
            *(uint4*)&Bs[n][ko * 8] = *(const uint4*)&xb[(size_t)(n0 + n) * C + k0 + ko * 8];
        }
        __syncthreads();
        short8 af[4], bf[4];
        #pragma unroll
        for (int mt = 0; mt < 4; ++mt)
            af[mt] = *(const short8*)&As[mt * 16 + l15][quad * 8];
        #pragma unroll
        for (int nt = 0; nt < 4; ++nt)
            bf[nt] = *(const short8*)&Bs[wave * 64 + nt * 16 + l15][quad * 8];
        #pragma unroll
        for (int mt = 0; mt < 4; ++mt)
            #pragma unroll
            for (int nt = 0; nt < 4; ++nt)
                acc[mt][nt] = __builtin_amdgcn_mfma_f32_16x16x32_bf16(
                    af[mt], bf[nt], acc[mt][nt], 0, 0, 0);
        __syncthreads();
    }
    unsigned short* ob = out + (size_t)b * OC * N;
    #pragma unroll
    for (int mt = 0; mt < 4; ++mt)
        #pragma unroll
        for (int r = 0; r < 4; ++r) {
            int o = m0 + mt * 16 + quad * 4 + r;
            #pragma unroll
            for (int nt = 0; nt < 4; ++nt)
                ob[(size_t)o * N + n0 + wave * 64 + nt * 16 + l15] =
                    f2bf(acc[mt][nt][r]);
        }
}

// ---------------------------------------------------------------------------
// K4: depthwise 3x3 (LDS-tiled) + mask + normsq
// ---------------------------------------------------------------------------
__global__ __launch_bounds__(256) void k_dwconv(
    const unsigned short* __restrict__ qkv_raw, const float* __restrict__ dw_w,
    const float* __restrict__ mask_single, unsigned short* __restrict__ qk_out,
    unsigned short* __restrict__ v_out, float* __restrict__ normsq) {
    __shared__ float tile[34][130];
    __shared__ float red[4];
    int tid = threadIdx.x;
    int b = blockIdx.z, o = blockIdx.y;
    int y0 = blockIdx.x * 32;
    const unsigned short* in = qkv_raw + ((size_t)b * OC + o) * N;
    for (int i = tid; i < 34 * 64; i += 256) {
        int r = i >> 6, dw = i & 63;
        int yy = y0 + r - 1;
        float fx = 0.f, fy = 0.f;
        if (yy >= 0 && yy < H) {
            unsigned int u = *(const unsigned int*)&in[yy * W + dw * 2];
            union { unsigned int i; float f; } lo, hi;
            lo.i = u << 16; hi.i = u & 0xffff0000u;
            fx = lo.f; fy = hi.f;
        }
        tile[r][1 + dw * 2] = fx;
        tile[r][2 + dw * 2] = fy;
        if (dw == 0) tile[r][0] = 0.f;
        if (dw == 63) tile[r][129] = 0.f;
    }
    __syncthreads();
    const float* wp = dw_w + o * 9;
    float w00 = wp[0], w01 = wp[1], w02 = wp[2];
    float w10 = wp[3], w11 = wp[4], w12 = wp[5];
    float w20 = wp[6], w21 = wp[7], w22 = wp[8];
    int c = tid & 127, g = tid >> 7;
    bool is_qk = (o < 2 * C);
    float m_acc = 0.f;
    int rbase = g * 16;
    float r0c0 = tile[rbase][c],     r0c1 = tile[rbase][c + 1],     r0c2 = tile[rbase][c + 2];
    float r1c0 = tile[rbase + 1][c], r1c1 = tile[rbase + 1][c + 1], r1c2 = tile[rbase + 1][c + 2];
    unsigned short* qkb = qk_out + ((size_t)b * 2 * C + o) * N;
    unsigned short* vb  = v_out + ((size_t)b * C + (o - 2 * C)) * N;
    const float* mb = mask_single + (size_t)b * N;
    #pragma unroll
    for (int rl = 0; rl < 16; ++rl) {
        int tr = rbase + rl + 2;
        float r2c0 = tile[tr][c], r2c1 = tile[tr][c + 1], r2c2 = tile[tr][c + 2];
        float s = w00 * r0c0 + w01 * r0c1 + w02 * r0c2
                + w10 * r1c0 + w11 * r1c1 + w12 * r1c2
                + w20 * r2c0 + w21 * r2c1 + w22 * r2c2;
        int p = (y0 + rbase + rl) * W + c;
        if (is_qk) s *= mb[p];
        unsigned short hv = f2bf(s);
        if (is_qk) {
            qkb[p] = hv;
            float fv = bf2f(hv);
            m_acc += fv * fv;
        } else {
            vb[p] = hv;
        }
        r0c0 = r1c0; r0c1 = r1c1; r0c2 = r1c2;
        r1c0 = r2c0; r1c1 = r2c1; r1c2 = r2c2;
    }
    if (is_qk) {
        #pragma unroll
        for (int off = 32; off > 0; off >>= 1) m_acc += __shfl_down(m_acc, off);
        if ((tid & 63) == 0) red[tid >> 6] = m_acc;
        __syncthreads();
        if (tid == 0)
            atomicAdd(&normsq[b * 2 * C + o], red[0] + red[1] + red[2] + red[3]);
    }
}

// ---------------------------------------------------------------------------
// K5: transpose v bf16 [b][c][n] -> v_t [b][n][c]
// ---------------------------------------------------------------------------
__global__ __launch_bounds__(256) void k_xpose_v(
    const unsigned short* __restrict__ src, unsigned short* __restrict__ dst) {
    __shared__ unsigned short t[64][C + 2];
    int tid = threadIdx.x;
    int b = blockIdx.y, n0 = blockIdx.x * 64;
    const unsigned short* sb = src + (size_t)b * C * N;
    for (int i = tid; i < C * 32; i += 256) {
        int c = i >> 5, np = i & 31;
        unsigned int u = *(const unsigned int*)&sb[(size_t)c * N + n0 + np * 2];
        t[np * 2][c] = (unsigned short)(u & 0xffffu);
        t[np * 2 + 1][c] = (unsigned short)(u >> 16);
    }
    __syncthreads();
    unsigned short* db = dst + ((size_t)b * N + n0) * C;
    for (int i = tid; i < 64 * (C / 8); i += 256) {
        int nn = i / (C / 8), ch = i % (C / 8);
        union { unsigned short h[8]; uint4 u; } pk;
        #pragma unroll
        for (int j = 0; j < 8; ++j) pk.h[j] = t[nn][ch * 8 + j];
        *(uint4*)&db[(size_t)nn * C + ch * 8] = pk.u;
    }
}

// ---------------------------------------------------------------------------
// K6: Gram via MFMA: G[b][h][i][j] = sum_n q[i][n]*k[j][n].
// Fragments load DIRECTLY from global (q,k stored [channel][n], n contiguous):
//   a-frag lane: q[i0 + (lane&15)][n_off + (lane>>4)*8 + 0..7]  (16B)
//   b-frag lane: k[j0 + (lane&15)][n_off + (lane>>4)*8 + 0..7]  (16B)
// Each wave: 3x3 tiles of 16x16 over CH=48; 4 waves split the n range;
// LDS cross-wave reduce; global fp32 atomicAdd.
// ---------------------------------------------------------------------------
__global__ __launch_bounds__(256) void k_gram_mfma(
    const unsigned short* __restrict__ qk, float* __restrict__ G) {
    __shared__ float Gs[4][CH][CH];
    int tid = threadIdx.x, wave = tid >> 6, lane = tid & 63;
    int l15 = lane & 15, quad = lane >> 4;
    int b = blockIdx.z, hh = blockIdx.y;
    int nb = blockIdx.x * 512 + wave * 128;
    const unsigned short* qb = qk + ((size_t)b * 2 * C + hh * CH) * N;
    const unsigned short* kb = qb + (size_t)C * N;
    floatx4 acc[3][3];
    #pragma unroll
    for (int i = 0; i < 3; ++i)
        #pragma unroll
        for (int j = 0; j < 3; ++j) acc[i][j] = (floatx4){0.f, 0.f, 0.f, 0.f};
    #pragma unroll
    for (int ks = 0; ks < 4; ++ks) {
        int n_off = nb + ks * 32 + quad * 8;
        short8 af[3], bf[3];
        #pragma unroll
        for (int it = 0; it < 3; ++it)
            af[it] = *(const short8*)&qb[(size_t)(it * 16 + l15) * N + n_off];
        #pragma unroll
        for (int jt = 0; jt < 3; ++jt)
            bf[jt] = *(const short8*)&kb[(size_t)(jt * 16 + l15) * N + n_off];
        #pragma unroll
        for (int it = 0; it < 3; ++it)
            #pragma unroll
            for (int jt = 0; jt < 3; ++jt)
                acc[it][jt] = __builtin_amdgcn_mfma_f32_16x16x32_bf16(
                    af[it], bf[jt], acc[it][jt], 0, 0, 0);
    }
    #pragma unroll
    for (int it = 0; it < 3; ++it)
        #pragma unroll
        for (int jt = 0; jt < 3; ++jt)
            #pragma unroll
            for (int r = 0; r < 4; ++r)
                Gs[wave][it * 16 + quad * 4 + r][jt * 16 + l15] = acc[it][jt][r];
    __syncthreads();
    float* Gb = G + (size_t)(b * HEADS + hh) * CH * CH;
    for (int idx = tid; idx < CH * CH; idx += 256) {
        int i = idx / CH, j = idx % CH;
        atomicAdd(&Gb[idx], Gs[0][i][j] + Gs[1][i][j] + Gs[2][i][j] + Gs[3][i][j]);
    }
}

// ---------------------------------------------------------------------------
// K7: softmax(G*temp/(|q||k|)) folded into proj -> W_eff bf16 [b][o][c]
// ---------------------------------------------------------------------------
__global__ __launch_bounds__(256) void k_attn_weff(
    const float* __restrict__ G, const float* __restrict__ normsq,
    const float* __restrict__ temperature, const float* __restrict__ proj_w,
    unsigned short* __restrict__ W_eff) {
    int b = blockIdx.x;
    int o_base = blockIdx.y * 32;
    __shared__ float attn[HEADS][CH][CH];
    __shared__ float inv_n[2 * C];
    int tid = threadIdx.x;
    for (int l = tid; l < 2 * C; l += 256)
        inv_n[l] = 1.0f / fmaxf(sqrtf(normsq[b * 2 * C + l]), 1e-12f);
    __syncthreads();
    if (tid < HEADS * CH) {
        int hh = tid / CH, i = tid % CH;
        float iq = inv_n[hh * CH + i] * temperature[hh];
        const float* Gr = G + ((size_t)(b * HEADS + hh) * CH + i) * CH;
        float mx = -1e30f;
        for (int j = 0; j < CH; ++j) {
            float l2 = Gr[j] * iq * inv_n[C + hh * CH + j];
            attn[hh][i][j] = l2;
            mx = fmaxf(mx, l2);
        }
        float sm = 0.0f;
        for (int j = 0; j < CH; ++j) {
            float e = expf(attn[hh][i][j] - mx);
            attn[hh][i][j] = e;
            sm += e;
        }
        float is = 1.0f / sm;
        for (int j = 0; j < CH; ++j) attn[hh][i][j] *= is;
    }
    __syncthreads();
    for (int idx = tid; idx < 32 * C; idx += 256) {
        int o = o_base + idx / C, cp = idx % C;
        int hh = cp / CH, j = cp % CH;
        const float* pw = proj_w + (size_t)o * C + hh * CH;
        float s = 0.0f;
        #pragma unroll 8
        for (int i = 0; i < CH; ++i) s += pw[i] * attn[hh][i][j];
        W_eff[((size_t)b * C + o) * C + cp] = f2bf(s);
    }
}

// ---------------------------------------------------------------------------
// K8: out = W_eff[b] (192x192) @ v_t^T -> fp32, MFMA. Tile 64m x 256n.
// ---------------------------------------------------------------------------
__global__ __launch_bounds__(256) void k_out_mfma(
    const unsigned short* __restrict__ vt, const unsigned short* __restrict__ W_eff,
    float* __restrict__ out) {
    __shared__ __align__(16) unsigned short As[64][PAD];
    __shared__ __align__(16) unsigned short Bs[256][PAD];
    int b = blockIdx.z, m0 = blockIdx.y * 64, n0 = blockIdx.x * 256;
    int tid = threadIdx.x, wave = tid >> 6, lane = tid & 63;
    int l15 = lane & 15, quad = lane >> 4;
    floatx4 acc[4][4];
    #pragma unroll
    for (int i = 0; i < 4; ++i)
        #pragma unroll
        for (int j = 0; j < 4; ++j) acc[i][j] = (floatx4){0.f, 0.f, 0.f, 0.f};
    const unsigned short* vb = vt + (size_t)b * N * C;
    const unsigned short* wb = W_eff + (size_t)b * C * C;
    for (int k0 = 0; k0 < C; k0 += 32) {
        {
            int m = tid >> 2, ko = tid & 3;
            *(uint4*)&As[m][ko * 8] = *(const uint4*)&wb[(size_t)(m0 + m) * C + k0 + ko * 8];
        }
        #pragma unroll
        for (int t = 0; t < 4; ++t) {
            int i = tid + t * 256;
            int n = i >> 2, ko = i & 3;
            *(uint4*)&Bs[n][ko * 8] = *(const uint4*)&vb[(size_t)(n0 + n) * C + k0 + ko * 8];
        }
        __syncthreads();
        short8 af[4], bf[4];
        #pragma unroll
        for (int mt = 0; mt < 4; ++mt)
            af[mt] = *(const short8*)&As[mt * 16 + l15][quad * 8];
        #pragma unroll
        for (int nt = 0; nt < 4; ++nt)
            bf[nt] = *(const short8*)&Bs[wave * 64 + nt * 16 + l15][quad * 8];
        #pragma unroll
        for (int mt = 0; mt < 4; ++mt)
            #pragma unroll
            for (int nt = 0; nt < 4; ++nt)
                acc[mt][nt] = __builtin_amdgcn_mfma_f32_16x16x32_bf16(
                    af[mt], bf[nt], acc[mt][nt], 0, 0, 0);
        __syncthreads();
    }
    float* ob = out + (size_t)b * C * N;
    #pragma unroll
    for (int mt = 0; mt < 4; ++mt)
        #pragma unroll
        for (int r = 0; r < 4; ++r) {
            int o = m0 + mt * 16 + quad * 4 + r;
            #pragma unroll
            for (int nt = 0; nt < 4; ++nt)
                ob[(size_t)o * N + n0 + wave * 64 + nt * 16 + l15] = acc[mt][nt][r];
        }
}

// ---------------------------------------------------------------------------
extern "C" void kernel_launch(void* const* d_in, const int* in_sizes, int n_in,
                              void* d_out, int out_size, void* d_ws, size_t ws_size,
                              hipStream_t stream) {
    const float* x           = (const float*)d_in[0];
    const float* inp         = (const float*)d_in[1];
    const float* qkv_w       = (const float*)d_in[2];
    const float* dw_w        = (const float*)d_in[3];
    const float* proj_w      = (const float*)d_in[4];
    const float* cm_w        = (const float*)d_in[5];
    const float* temperature = (const float*)d_in[6];
    const float* threshold   = (const float*)d_in[7];
    float* out = (float*)d_out;

    char* ws = (char*)d_ws;
    const size_t SZ_RAW = (size_t)B * OC * N * 2;      // 150,994,944
    const size_t SZ_QK  = (size_t)B * 2 * C * N * 2;   // 100,663,296
    const size_t SZ_XT  = (size_t)B * N * C * 2;       //  50,331,648
    unsigned short* qkv_raw = (unsigned short*)ws;
    unsigned short* v_t     = (unsigned short*)ws;                       // reuse
    unsigned short* qk      = (unsigned short*)(ws + SZ_RAW);
    unsigned short* xt      = (unsigned short*)(ws + SZ_RAW + SZ_QK);
    unsigned short* vbuf    = xt;                                        // reuse
    char* tail = ws + SZ_RAW + SZ_QK + SZ_XT;
    float* mask_single = (float*)tail;
    float* normsq = (float*)(tail + (size_t)B * N * 4);
    float* G = normsq + B * 2 * C;
    unsigned short* W_eff = (unsigned short*)(G + B * HEADS * CH * CH);

    k_zero<<<dim3((B * HEADS * CH * CH + 255) / 256), 256, 0, stream>>>(normsq, G);
    k_mask_xt<<<dim3(N / 64, B), 256, 0, stream>>>(x, inp, cm_w, threshold, mask_single, xt);
    k_qkv_mfma<<<dim3(N / 256, OC / 64, B), 256, 0, stream>>>(xt, qkv_w, qkv_raw);
    k_dwconv<<<dim3(H / 32, OC, B), 256, 0, stream>>>(qkv_raw, dw_w, mask_single, qk, vbuf, normsq);
    k_xpose_v<<<dim3(N / 64, B), 256, 0, stream>>>(vbuf, v_t);
    k_gram_mfma<<<dim3(N / 512, HEADS, B), 256, 0, stream>>>(qk, G);
    k_attn_weff<<<dim3(B, 6), 256, 0, stream>>>(G, normsq, temperature, proj_w, W_eff);
    k_out_mfma<<<dim3(N / 256, C / 64, B), 256, 0, stream>>>(v_t, W_eff, out);
}